// Round 1
// baseline (392.915 us; speedup 1.0000x reference)
//
#include <hip/hip_runtime.h>

// S4 layer: y = C * scan(a_bar, dt*B*u) + u*D
// Decomposition:
//   prep:    dt_mean = mean(exp(log_dt)); A_bar = I + dt*A
//   matsq x6: A_pow = A_bar^64 (repeated squaring, ping-pong launches)
//   gemm1:   bu[m][n] = dt * sum_d u[m][d] * B[n][d]          (M=65536, N=64, K=1024)
//   scan<0>: per-chunk (64 steps) local scan from zero -> chunk end states E
//   combine: S_{j+1} = A_pow * S_j + E_j   (sequential over 64 chunks, per batch)
//   scan<1>: re-run recurrence with correct initial state; xs overwrites bu in place
//   gemm2:   y[m][d] = sum_n xs[m][n]*C[d][n] + u[m][d]*D[d]  (M=65536, N=1024, K=64)

#define DM   1024
#define DS   64
#define NB   16
#define LL   4096
#define LC   64
#define NCH  (LL / LC)     // 64 chunks per batch
#define MTOT (NB * LL)     // 65536

// workspace layout in floats
#define WS_ABAR 64
#define WS_APOW (WS_ABAR + 4096)          // 4160
#define WS_TMP  (WS_APOW + 4096)          // 8256
#define WS_E    (WS_TMP + 4096)           // 12352
#define WS_S    (WS_E + NB * NCH * DS)    // 77888
#define WS_BU   (WS_S + NB * NCH * DS)    // 143424
// total floats = 143424 + 65536*64 = 4,337,728  (~17.35 MB)

__global__ __launch_bounds__(256) void k_prep(const float* __restrict__ A,
                                              const float* __restrict__ log_dt,
                                              float* __restrict__ ws) {
    __shared__ float red[256];
    int tid = threadIdx.x;
    float s = 0.f;
    for (int i = tid; i < DM; i += 256) s += expf(log_dt[i]);
    red[tid] = s;
    __syncthreads();
    for (int off = 128; off > 0; off >>= 1) {
        if (tid < off) red[tid] += red[tid + off];
        __syncthreads();
    }
    float dt = red[0] * (1.f / (float)DM);
    if (tid == 0) ws[0] = dt;
    for (int idx = tid; idx < 4096; idx += 256) {
        int n = idx >> 6, m = idx & 63;
        ws[WS_ABAR + idx] = dt * A[idx] + ((n == m) ? 1.f : 0.f);
    }
}

// dst = src*src for a 64x64 matrix. grid=16 blocks x 256 thr (1 output/thread).
__global__ __launch_bounds__(256) void k_matsq(const float* __restrict__ src,
                                               float* __restrict__ dst) {
    __shared__ float s[64][65];
    int tid = threadIdx.x;
#pragma unroll
    for (int rep = 0; rep < 16; ++rep) {
        int idx = rep * 256 + tid;
        s[idx >> 6][idx & 63] = src[idx];
    }
    __syncthreads();
    int n = (blockIdx.x << 2) + (tid >> 6);  // wave-uniform row
    int m = tid & 63;
    float acc = 0.f;
#pragma unroll
    for (int k = 0; k < 64; ++k) acc = fmaf(s[n][k], s[k][m], acc);
    dst[(n << 6) + m] = acc;
}

// bu[m][n] = dt * sum_k u[m][k] * B[n][k]. Tile 128 rows x 64 cols, K-tiles of 64.
// Per thread: 4 rows (r = rg + 32*i, strided -> conflict-free broadcast reads)
//             x 8 cols (c = 4*c8 + 32*h).
__global__ __launch_bounds__(256) void k_gemm1(const float* __restrict__ u,
                                               const float* __restrict__ Bm,
                                               const float* __restrict__ ws,
                                               float* __restrict__ bu) {
    __shared__ float u_lds[128][68];   // pad 68: bank(4*rg + k) spreads row groups
    __shared__ float bt_lds[64][68];   // B transposed: bt[k][n]
    int tid = threadIdx.x;
    int m0 = blockIdx.x * 128;
    float dt = ws[0];
    int rg = tid >> 3, c8 = tid & 7;
    float acc[4][8];
#pragma unroll
    for (int i = 0; i < 4; ++i)
#pragma unroll
        for (int j = 0; j < 8; ++j) acc[i][j] = 0.f;

    for (int kt = 0; kt < 16; ++kt) {
        int k0 = kt * 64;
#pragma unroll
        for (int rep = 0; rep < 8; ++rep) {           // stage u tile (128x64)
            int idx = rep * 256 + tid;
            int r = idx >> 4, c4 = (idx & 15) << 2;
            float4 v = *reinterpret_cast<const float4*>(&u[(size_t)(m0 + r) * DM + k0 + c4]);
            *reinterpret_cast<float4*>(&u_lds[r][c4]) = v;
        }
#pragma unroll
        for (int rep = 0; rep < 16; ++rep) {          // stage B^T tile (64x64)
            int idx = rep * 256 + tid;
            int n = idx >> 6, k = idx & 63;
            bt_lds[k][n] = Bm[n * DM + k0 + k];
        }
        __syncthreads();
#pragma unroll
        for (int k4 = 0; k4 < 64; k4 += 4) {
            float4 a[4];
#pragma unroll
            for (int i = 0; i < 4; ++i)
                a[i] = *reinterpret_cast<float4*>(&u_lds[rg + 32 * i][k4]);
            float4 b0[4], b1[4];
#pragma unroll
            for (int kk = 0; kk < 4; ++kk) {
                b0[kk] = *reinterpret_cast<float4*>(&bt_lds[k4 + kk][c8 * 4]);
                b1[kk] = *reinterpret_cast<float4*>(&bt_lds[k4 + kk][c8 * 4 + 32]);
            }
#pragma unroll
            for (int i = 0; i < 4; ++i) {
                float av[4] = {a[i].x, a[i].y, a[i].z, a[i].w};
#pragma unroll
                for (int kk = 0; kk < 4; ++kk) {
                    acc[i][0] = fmaf(av[kk], b0[kk].x, acc[i][0]);
                    acc[i][1] = fmaf(av[kk], b0[kk].y, acc[i][1]);
                    acc[i][2] = fmaf(av[kk], b0[kk].z, acc[i][2]);
                    acc[i][3] = fmaf(av[kk], b0[kk].w, acc[i][3]);
                    acc[i][4] = fmaf(av[kk], b1[kk].x, acc[i][4]);
                    acc[i][5] = fmaf(av[kk], b1[kk].y, acc[i][5]);
                    acc[i][6] = fmaf(av[kk], b1[kk].z, acc[i][6]);
                    acc[i][7] = fmaf(av[kk], b1[kk].w, acc[i][7]);
                }
            }
        }
        __syncthreads();
    }
#pragma unroll
    for (int i = 0; i < 4; ++i) {
        size_t row = (size_t)(m0 + rg + 32 * i);
#pragma unroll
        for (int h = 0; h < 2; ++h) {
            float4 o;
            o.x = dt * acc[i][h * 4 + 0];
            o.y = dt * acc[i][h * 4 + 1];
            o.z = dt * acc[i][h * 4 + 2];
            o.w = dt * acc[i][h * 4 + 3];
            *reinterpret_cast<float4*>(&bu[row * DS + c8 * 4 + 32 * h]) = o;
        }
    }
}

// Chunked scan. One wave per (batch, chunk) task; lane n holds state x[n] and
// row n of A_bar in 64 VGPRs. State broadcast via per-wave LDS buffer
// (all-lane same-address float4 reads = free broadcast; intra-wave LDS is in-order).
// PASS 0: from zero init, write chunk end state E. PASS 1: from S_j, write xs in place.
template <int PASS>
__global__ __launch_bounds__(256) void k_scan(float* __restrict__ ws) {
    const float* Abar = ws + WS_ABAR;
    float* bu = ws + WS_BU;
    int tid = threadIdx.x;
    int w = tid >> 6, lane = tid & 63;
    int task = blockIdx.x * 4 + w;          // task = b*NCH + j
    int b = task >> 6;
    int j = task & 63;
    __shared__ float xbuf[4][64];

    float a_row[64];
#pragma unroll
    for (int mg = 0; mg < 16; ++mg) {
        float4 v = *reinterpret_cast<const float4*>(&Abar[lane * 64 + mg * 4]);
        a_row[mg * 4 + 0] = v.x; a_row[mg * 4 + 1] = v.y;
        a_row[mg * 4 + 2] = v.z; a_row[mg * 4 + 3] = v.w;
    }
    float x;
    if (PASS == 0) x = 0.f;
    else           x = ws[WS_S + (size_t)task * DS + lane];

    float* bub = bu + ((size_t)b * LL + (size_t)j * LC) * DS;
    float buv = bub[lane];
    for (int t = 0; t < LC; ++t) {
        float bunext = 0.f;
        if (t + 1 < LC) bunext = bub[(t + 1) * DS + lane];  // prefetch hides latency
        xbuf[w][lane] = x;
        asm volatile("" ::: "memory");
        float xn = buv;
#pragma unroll
        for (int mg = 0; mg < 16; ++mg) {
            float4 xm = *reinterpret_cast<float4*>(&xbuf[w][mg * 4]);
            xn = fmaf(a_row[mg * 4 + 0], xm.x, xn);
            xn = fmaf(a_row[mg * 4 + 1], xm.y, xn);
            xn = fmaf(a_row[mg * 4 + 2], xm.z, xn);
            xn = fmaf(a_row[mg * 4 + 3], xm.w, xn);
        }
        asm volatile("" ::: "memory");
        x = xn;
        if (PASS == 1) bub[t * DS + lane] = x;
        buv = bunext;
    }
    if (PASS == 0) ws[WS_E + (size_t)task * DS + lane] = x;
}

// Sequential chunk-boundary propagation: one wave per batch.
// S_0 = 0; S_{j+1} = A_pow * S_j + E_j.  Writes S_j before updating.
__global__ __launch_bounds__(64) void k_combine(float* __restrict__ ws) {
    const float* Apow = ws + WS_APOW;
    int b = blockIdx.x;
    int lane = threadIdx.x;
    __shared__ float xbuf[64];
    float p_row[64];
#pragma unroll
    for (int mg = 0; mg < 16; ++mg) {
        float4 v = *reinterpret_cast<const float4*>(&Apow[lane * 64 + mg * 4]);
        p_row[mg * 4 + 0] = v.x; p_row[mg * 4 + 1] = v.y;
        p_row[mg * 4 + 2] = v.z; p_row[mg * 4 + 3] = v.w;
    }
    float x = 0.f;
    for (int jj = 0; jj < NCH; ++jj) {
        size_t task = (size_t)b * NCH + jj;
        ws[WS_S + task * DS + lane] = x;
        float e = ws[WS_E + task * DS + lane];
        xbuf[lane] = x;
        asm volatile("" ::: "memory");
        float xn = e;
#pragma unroll
        for (int mg = 0; mg < 16; ++mg) {
            float4 xm = *reinterpret_cast<float4*>(&xbuf[mg * 4]);
            xn = fmaf(p_row[mg * 4 + 0], xm.x, xn);
            xn = fmaf(p_row[mg * 4 + 1], xm.y, xn);
            xn = fmaf(p_row[mg * 4 + 2], xm.z, xn);
            xn = fmaf(p_row[mg * 4 + 3], xm.w, xn);
        }
        asm volatile("" ::: "memory");
        x = xn;
    }
}

// y[m][d] = sum_n xs[m][n]*C[d][n] + u[m][d]*D[d]. Tile 128 m x 128 d, K=64 full.
// Per thread: 4 rows (strided) x 16 cols (4 float4 groups spread across the tile).
__global__ __launch_bounds__(256) void k_gemm2(const float* __restrict__ u,
                                               const float* __restrict__ C,
                                               const float* __restrict__ Dv,
                                               const float* __restrict__ ws,
                                               float* __restrict__ y) {
    __shared__ float xs_lds[128][68];
    __shared__ float ct_lds[64][132];   // C transposed: ct[n][d_local]
    const float* xs = ws + WS_BU;
    int tid = threadIdx.x;
    int m0 = blockIdx.x * 128;
    int d0 = blockIdx.y * 128;
#pragma unroll
    for (int rep = 0; rep < 8; ++rep) {            // stage xs tile (128x64)
        int idx = rep * 256 + tid;
        int r = idx >> 4, c4 = (idx & 15) << 2;
        float4 v = *reinterpret_cast<const float4*>(&xs[(size_t)(m0 + r) * DS + c4]);
        *reinterpret_cast<float4*>(&xs_lds[r][c4]) = v;
    }
#pragma unroll
    for (int rep = 0; rep < 32; ++rep) {           // stage C^T tile (64x128)
        int idx = rep * 256 + tid;
        int n = idx & 63, dl = idx >> 6;
        ct_lds[n][dl] = C[(size_t)(d0 + dl) * DS + n];
    }
    __syncthreads();

    int rg = tid >> 3, c8 = tid & 7;
    float acc[4][16];
#pragma unroll
    for (int i = 0; i < 4; ++i)
#pragma unroll
        for (int j = 0; j < 16; ++j) acc[i][j] = 0.f;

#pragma unroll 4
    for (int n = 0; n < 64; ++n) {
        float xv[4];
#pragma unroll
        for (int i = 0; i < 4; ++i) xv[i] = xs_lds[rg + 32 * i][n];
        float4 cv[4];
#pragma unroll
        for (int q = 0; q < 4; ++q)
            cv[q] = *reinterpret_cast<float4*>(&ct_lds[n][c8 * 4 + 32 * q]);
#pragma unroll
        for (int i = 0; i < 4; ++i) {
#pragma unroll
            for (int q = 0; q < 4; ++q) {
                acc[i][q * 4 + 0] = fmaf(xv[i], cv[q].x, acc[i][q * 4 + 0]);
                acc[i][q * 4 + 1] = fmaf(xv[i], cv[q].y, acc[i][q * 4 + 1]);
                acc[i][q * 4 + 2] = fmaf(xv[i], cv[q].z, acc[i][q * 4 + 2]);
                acc[i][q * 4 + 3] = fmaf(xv[i], cv[q].w, acc[i][q * 4 + 3]);
            }
        }
    }
#pragma unroll
    for (int i = 0; i < 4; ++i) {
        size_t row = (size_t)(m0 + rg + 32 * i);
#pragma unroll
        for (int q = 0; q < 4; ++q) {
            int c = d0 + c8 * 4 + 32 * q;
            float4 uv = *reinterpret_cast<const float4*>(&u[row * DM + c]);
            float4 dv = *reinterpret_cast<const float4*>(&Dv[c]);
            float4 o;
            o.x = acc[i][q * 4 + 0] + uv.x * dv.x;
            o.y = acc[i][q * 4 + 1] + uv.y * dv.y;
            o.z = acc[i][q * 4 + 2] + uv.z * dv.z;
            o.w = acc[i][q * 4 + 3] + uv.w * dv.w;
            *reinterpret_cast<float4*>(&y[row * DM + c]) = o;
        }
    }
}

extern "C" void kernel_launch(void* const* d_in, const int* in_sizes, int n_in,
                              void* d_out, int out_size, void* d_ws, size_t ws_size,
                              hipStream_t stream) {
    (void)in_sizes; (void)n_in; (void)out_size; (void)ws_size;
    const float* u      = (const float*)d_in[0];
    const float* A      = (const float*)d_in[1];
    const float* Bm     = (const float*)d_in[2];
    const float* C      = (const float*)d_in[3];
    const float* Dv     = (const float*)d_in[4];
    const float* log_dt = (const float*)d_in[5];
    float* y  = (float*)d_out;
    float* ws = (float*)d_ws;
    float* bu = ws + WS_BU;

    k_prep<<<dim3(1), dim3(256), 0, stream>>>(A, log_dt, ws);
    // A_pow = A_bar^64 via 6 squarings (ping-pong so the result lands in WS_APOW)
    k_matsq<<<dim3(16), dim3(256), 0, stream>>>(ws + WS_ABAR, ws + WS_TMP);   // A^2
    k_matsq<<<dim3(16), dim3(256), 0, stream>>>(ws + WS_TMP,  ws + WS_APOW);  // A^4
    k_matsq<<<dim3(16), dim3(256), 0, stream>>>(ws + WS_APOW, ws + WS_TMP);   // A^8
    k_matsq<<<dim3(16), dim3(256), 0, stream>>>(ws + WS_TMP,  ws + WS_APOW);  // A^16
    k_matsq<<<dim3(16), dim3(256), 0, stream>>>(ws + WS_APOW, ws + WS_TMP);   // A^32
    k_matsq<<<dim3(16), dim3(256), 0, stream>>>(ws + WS_TMP,  ws + WS_APOW);  // A^64

    k_gemm1<<<dim3(MTOT / 128), dim3(256), 0, stream>>>(u, Bm, ws, bu);
    k_scan<0><<<dim3(NB * NCH / 4), dim3(256), 0, stream>>>(ws);
    k_combine<<<dim3(NB), dim3(64), 0, stream>>>(ws);
    k_scan<1><<<dim3(NB * NCH / 4), dim3(256), 0, stream>>>(ws);
    k_gemm2<<<dim3(MTOT / 128, DM / 128), dim3(256), 0, stream>>>(u, C, Dv, ws, y);
}